// Round 7
// baseline (373.060 us; speedup 1.0000x reference)
//
#include <hip/hip_runtime.h>
#include <math.h>

typedef __attribute__((ext_vector_type(8))) __bf16 bf16x8;
typedef __attribute__((ext_vector_type(4))) float f32x4;
typedef __attribute__((ext_vector_type(4))) unsigned short us4;
typedef unsigned short u16;
typedef unsigned int u32;

#define DEVI static __device__ __forceinline__

// round-to-nearest-even fp32 -> bf16
DEVI u16 f2bf(float f) {
  union { float f; unsigned u; } v; v.f = f;
  unsigned r = v.u + 0x7fffu + ((v.u >> 16) & 1u);
  return (u16)(r >> 16);
}

DEVI void async16(const void* g, void* l) {
  __builtin_amdgcn_global_load_lds((const __attribute__((address_space(1))) void*)g,
                                   (__attribute__((address_space(3))) void*)l, 16, 0, 0);
}

// pack two f32 -> one u32 of 2 bf16 (RNE)
DEVI u32 pkbf(float lo, float hi) {
  u32 r;
  asm("v_cvt_pk_bf16_f32 %0, %1, %2" : "=v"(r) : "v"(lo), "v"(hi));
  return r;
}

// ---------------- cast fp32 -> bf16 ----------------
__global__ __launch_bounds__(256) void cast_bf16(const float* __restrict__ in,
                                                 u16* __restrict__ out, int n) {
  int i = (blockIdx.x * 256 + threadIdx.x) * 4;
  if (i >= n) return;
  float4 v = *(const float4*)(in + i);
  us4 o = { f2bf(v.x), f2bf(v.y), f2bf(v.z), f2bf(v.w) };
  *(us4*)(out + i) = o;
}

// ---------- 256x256 GEMM, true 8-phase schedule (m201 port) ----------
// BK=64, 2 K-tiles per iteration, 8 waves (2Mx4N), per-wave 128x64.
// LDS 2 x 64KB (A 32KB + B 32KB per K-tile), XOR swizzle (row&7)<<4,
// inverse-swizzled global source, linear gload_lds dest (G21).
// Phase: {ds_read subtile; stage 1 half-tile (2 gloads); [lgkm(8) hint];
//         barrier; lgkmcnt(0)+sched_barrier; setprio(1); 16 MFMA; setprio(0);
//         barrier}. vmcnt(4) only at ph4/ph8 (2 half-tiles stay in flight).
__global__ __launch_bounds__(512, 2)
void gemm256(const u16* __restrict__ A,
             const u16* __restrict__ W0, const u16* __restrict__ W1, const u16* __restrict__ W2,
             const float* __restrict__ biasQ, const float* __restrict__ biasK,
             const float* __restrict__ biasV,
             const float* __restrict__ cosT, const float* __restrict__ sinT,
             void* __restrict__ out0, void* __restrict__ out1, void* __restrict__ out2,
             int ntn, int qkv)
{
  __shared__ __align__(16) char lds[2 * 65536];
  const int t = threadIdx.x, w = t >> 6, lane = t & 63;
  const int lrow = lane & 15, g = lane >> 4, lk8 = g * 8;
  // XCD-stripe decode
  const int xcd = blockIdx.x & 7, bi = blockIdx.x >> 3;
  const int ntpx = ntn >> 3;
  const int nt = xcd * ntpx + (ntpx > 1 ? bi % ntpx : 0);
  const int mt = ntpx > 1 ? bi / ntpx : bi;
  const int slab = qkv ? (nt >> 3) : 3;
  const u16* Bp = (slab == 1) ? W1 : (slab == 2) ? W2 : W0;
  const int brow = mt * 256;
  const int bcol = (qkv ? (nt & 7) : nt) * 256;
  const int wm = w >> 2, wn = w & 3;

  // staging: half h in {0=A0,1=A1,2=B0,3=B1} (128 rows x 64 k = 16KB),
  // 2 gloads/thread; global source inverse-swizzled, LDS dest linear.
  u32 soff[4][2]; int lbyte[4][2];
#pragma unroll
  for (int h = 0; h < 4; ++h)
#pragma unroll
    for (int l = 0; l < 2; ++l) {
      const int q = (h & 1) * 16384 + (l * 512 + t) * 16;   // byte in 32KB region
      const int row = q >> 7;
      const int cb = (q ^ ((row & 7) << 4)) & 127;
      soff[h][l] = (u32)(((h < 2 ? brow : bcol) + row) * 2048 + (cb >> 1));
      lbyte[h][l] = (h & 1) * 16384 + (h >> 1) * 32768 + (l * 512 + t) * 16;
    }
  auto stg = [&](int tile, int h, int b) {
    const u16* src = (h < 2) ? A : Bp;
#pragma unroll
    for (int l = 0; l < 2; ++l)
      async16(src + soff[h][l] + tile * 64, lds + b * 65536 + lbyte[h][l]);
  };

  // fragment read offsets (swizzled)
  int offA[8][2], offB[4][2];
#pragma unroll
  for (int mi = 0; mi < 8; ++mi)
#pragma unroll
    for (int kk = 0; kk < 2; ++kk) {
      const int row = wm * 128 + mi * 16 + lrow;
      offA[mi][kk] = (row * 128 + (kk * 32 + lk8) * 2) ^ ((row & 7) << 4);
    }
#pragma unroll
  for (int ni = 0; ni < 4; ++ni)
#pragma unroll
    for (int kk = 0; kk < 2; ++kk) {
      const int row = wn * 64 + ni * 16 + lrow;
      offB[ni][kk] = 32768 + ((row * 128 + (kk * 32 + lk8) * 2) ^ ((row & 7) << 4));
    }

  f32x4 acc[8][4] = {};
  bf16x8 af[4][2], bf[4][2];

#define MFMA_QUAD(MOFF, NOFF)                                                   \
  _Pragma("unroll") for (int mi = 0; mi < 4; ++mi)                              \
  _Pragma("unroll") for (int ni = 0; ni < 2; ++ni)                              \
  _Pragma("unroll") for (int kk = 0; kk < 2; ++kk)                              \
    acc[MOFF + mi][NOFF + ni] = __builtin_amdgcn_mfma_f32_16x16x32_bf16(        \
        af[mi][kk], bf[NOFF + ni][kk], acc[MOFF + mi][NOFF + ni], 0, 0, 0);

#define RD_A(CBUF, MI0)                                                         \
  _Pragma("unroll") for (int i = 0; i < 4; ++i)                                 \
  _Pragma("unroll") for (int kk = 0; kk < 2; ++kk)                              \
    af[i][kk] = *(const bf16x8*)((CBUF) + offA[MI0 + i][kk]);

#define RD_B(CBUF, NI0)                                                         \
  _Pragma("unroll") for (int i = 0; i < 2; ++i)                                 \
  _Pragma("unroll") for (int kk = 0; kk < 2; ++kk)                              \
    bf[NI0 + i][kk] = *(const bf16x8*)((CBUF) + offB[NI0 + i][kk]);

#define BAR()  __builtin_amdgcn_s_barrier()
#define LGKM0() do { asm volatile("s_waitcnt lgkmcnt(0)" ::: "memory");         \
                     __builtin_amdgcn_sched_barrier(0); } while (0)
#define PRIO(x) __builtin_amdgcn_s_setprio(x)

  // prologue: tile0 all halves -> buf0; tile1 B-halves -> buf1
  stg(0, 0, 0); stg(0, 1, 0); stg(0, 2, 0); stg(0, 3, 0);
  stg(1, 2, 1); stg(1, 3, 1);
  asm volatile("s_waitcnt vmcnt(4)" ::: "memory");
  BAR();

  const int nIter = 16;   // K=2048 / (2*64)
  for (int j = 0; j < nIter; ++j) {
    const int T = 2 * j;
    const bool st = (j + 1) < nIter;
    char* c0 = lds;
    char* c1 = lds + 65536;

    // ---- ph1: Q00 of tile T; reads A0-3,B0-1 (12); stage A0(T+1)->buf1
    RD_A(c0, 0); RD_B(c0, 0);
    stg(T + 1, 0, 1);
    asm volatile("s_waitcnt lgkmcnt(8)" ::: "memory");
    BAR(); LGKM0(); PRIO(1);
    MFMA_QUAD(0, 0);
    PRIO(0); BAR();

    // ---- ph2: Q01; reads B2-3 (4); stage A1(T+1)->buf1
    RD_B(c0, 2);
    stg(T + 1, 1, 1);
    BAR(); LGKM0(); PRIO(1);
    MFMA_QUAD(0, 2);
    PRIO(0); BAR();

    // ---- ph3: Q10; reads A4-7 (8); stage B0(T+2)->buf0
    RD_A(c0, 4);
    if (st) stg(T + 2, 2, 0);
    BAR(); LGKM0(); PRIO(1);
    MFMA_QUAD(4, 0);
    PRIO(0); BAR();

    // ---- ph4: Q11; no reads; stage B1(T+2)->buf0; vmcnt fence for buf1
    if (st) stg(T + 2, 3, 0);
    BAR(); PRIO(1);
    MFMA_QUAD(4, 2);
    PRIO(0);
    if (st) asm volatile("s_waitcnt vmcnt(4)" ::: "memory");
    else    asm volatile("s_waitcnt vmcnt(0)" ::: "memory");
    BAR();

    // ---- ph5: Q00 of tile T+1; reads A0-3,B0-1; stage A0(T+2)->buf0
    RD_A(c1, 0); RD_B(c1, 0);
    if (st) stg(T + 2, 0, 0);
    asm volatile("s_waitcnt lgkmcnt(8)" ::: "memory");
    BAR(); LGKM0(); PRIO(1);
    MFMA_QUAD(0, 0);
    PRIO(0); BAR();

    // ---- ph6: Q01; reads B2-3; stage A1(T+2)->buf0
    RD_B(c1, 2);
    if (st) stg(T + 2, 1, 0);
    BAR(); LGKM0(); PRIO(1);
    MFMA_QUAD(0, 2);
    PRIO(0); BAR();

    // ---- ph7: Q10; reads A4-7; stage B0(T+3)->buf1
    RD_A(c1, 4);
    if (st) stg(T + 3, 2, 1);
    BAR(); LGKM0(); PRIO(1);
    MFMA_QUAD(4, 0);
    PRIO(0); BAR();

    // ---- ph8: Q11; no reads; stage B1(T+3)->buf1; vmcnt fence for buf0
    if (st) stg(T + 3, 3, 1);
    BAR(); PRIO(1);
    MFMA_QUAD(4, 2);
    PRIO(0);
    if (st) { asm volatile("s_waitcnt vmcnt(4)" ::: "memory"); }
    BAR();
  }

  // ---- epilogue ----
  const int g4 = g * 4;
#pragma unroll
  for (int mi = 0; mi < 8; ++mi) {
#pragma unroll
    for (int ni = 0; ni < 4; ++ni) {
      f32x4 v = acc[mi][ni];
      const int row0 = brow + wm * 128 + mi * 16 + g4;
      const int cols = bcol + wn * 64 + ni * 16 + lrow;
      if (slab == 3) {
        float* O = (float*)out0;
        const float bv = biasQ[cols];
#pragma unroll
        for (int r = 0; r < 4; ++r)
          O[(size_t)(row0 + r) * 2048 + cols] = v[r] + bv;
      } else if (slab == 2) {   // V -> Vt [B,H,HD,S], pi-permuted + swizzled
        u16* O = (u16*)out2;
        const float bv = biasV[cols];
        const int h = cols >> 7, d = cols & 127;
        const int bb = row0 >> 11, s = row0 & 2047;
        us4 ov;
#pragma unroll
        for (int r = 0; r < 4; ++r) ov[r] = f2bf(v[r] + bv);
        const int l = s & 63;
        const int kt = l >> 4, g2 = (l >> 2) & 3;
        const int c = ((kt >> 1) << 5) + (g2 << 3) + ((kt & 1) << 2);
        u16* base = O + ((size_t)(bb * 16 + h) * 128 + d) * 2048 + (s & ~63);
        *(us4*)((char*)base + ((unsigned)(c << 1) ^ (unsigned)((d & 7) << 4))) = ov;
      } else {                  // Q (0) / K (1): bias + RoPE
        u16* O = (u16*)(slab ? out1 : out0);
        const float bv = slab ? biasK[cols] : biasQ[cols];
        const int h = cols >> 7, d = cols & 127;
        const float sgn = (d & 1) ? 1.f : -1.f;
        const float QSCL = 0.08838834764831845f * 1.44269504088896340f;
#pragma unroll
        for (int r = 0; r < 4; ++r) {
          const int row = row0 + r, bb = row >> 11, s = row & 2047;
          float q = v[r] + bv;
          float p = __shfl_xor(q, 1);   // partner dim d^1 lives in lane^1
          float o = q * cosT[s * 128 + d] + sgn * p * sinT[s * 128 + d];
          u16* base = O + ((size_t)(bb * 16 + h) * 2048 + s) * 128;
          if (slab == 0) {
            base[d] = f2bf(o * QSCL);
          } else {
            *(u16*)((char*)base + (((unsigned)(d << 1)) ^ (unsigned)((s & 7) << 4))) = f2bf(o);
          }
        }
      }
    }
  }
}

// ---------------- causal flash attention ----------------
// Q: [BH][S][128] bf16 pre-scaled by 1/sqrt(128)*log2e, K: row-swizzled,
// Vt: [BH][128][S] pi-permuted + swizzled. AO out: [4096][2048] bf16.
__global__ __launch_bounds__(256, 2)
void attn_fwd(const u16* __restrict__ Q, const u16* __restrict__ K,
              const u16* __restrict__ Vt, u16* __restrict__ AO)
{
  __shared__ __align__(16) u16 Ks[2][64 * 128];
  __shared__ __align__(16) u16 Vs[2][128 * 64];
  const int t = threadIdx.x, w = t >> 6, lane = t & 63;
  const int lrow = lane & 15, g = lane >> 4, lk8 = g * 8;
  const int id = blockIdx.x;
  const int bh = (id & 7) | (((id >> 3) & 3) << 3);   // XCD-local bh grouping
  const int pr = id >> 5;                              // pair index 0..15
  const u16* Qg = Q + (size_t)bh * 2048 * 128;
  const u16* Kg = K + (size_t)bh * 2048 * 128;
  const u16* Vg = Vt + (size_t)bh * 128 * 2048;
  const int bb = bh >> 4, h = bh & 15;

  for (int half = 0; half < 2; ++half) {
    const int qt = half ? (31 - pr) : pr;
    const int q0 = qt * 64, qw = q0 + w * 16;
    const int nkv = qt + 1;
    const int qg = qw + lrow;   // this lane's q-row

    bf16x8 qf[4];
#pragma unroll
    for (int c = 0; c < 4; ++c)
      qf[c] = *(const bf16x8*)(Qg + (size_t)(qw + lrow) * 128 + lk8 + c * 32);

    f32x4 acc_o[8] = {};
    float m = -1e30f, lsum = 0.f;

    auto stage = [&](int i, int b) {
#pragma unroll
      for (int r = 0; r < 4; ++r) {
        int e = (r * 256 + t) * 8;
        async16(Kg + (size_t)i * 8192 + e, &Ks[b][r * 2048 + w * 512]);
        async16(Vg + (size_t)(e >> 6) * 2048 + i * 64 + (e & 63), &Vs[b][r * 2048 + w * 512]);
      }
    };

    stage(0, 0);
    for (int i = 0; i < nkv; ++i) {
      const int cur = i & 1;
      const bool pfch = (i + 1) < nkv;
      if (pfch) stage(i + 1, cur ^ 1);
      if (pfch) asm volatile("s_waitcnt vmcnt(8)" ::: "memory");
      else      asm volatile("s_waitcnt vmcnt(0)" ::: "memory");
      __builtin_amdgcn_s_barrier();
      __builtin_amdgcn_sched_barrier(0);

      // QK^T swapped: C col = q (lane&15), row = k
      f32x4 sc[4];
      __builtin_amdgcn_s_setprio(1);
#pragma unroll
      for (int kt = 0; kt < 4; ++kt) {
        f32x4 s = {};
        const int krow = kt * 16 + lrow;
        const char* kbase = (const char*)(&Ks[cur][krow * 128]);
        const unsigned sw = (unsigned)((krow & 7) << 4);
#pragma unroll
        for (int c = 0; c < 4; ++c) {
          bf16x8 kf = *(const bf16x8*)(kbase + ((unsigned)((lk8 + c * 32) << 1) ^ sw));
          s = __builtin_amdgcn_mfma_f32_16x16x32_bf16(kf, qf[c], s, 0, 0, 0);
        }
        sc[kt] = s;
      }
      __builtin_amdgcn_s_setprio(0);

      float p[4][4];
      const bool lastblk = (i == qt);
      if (lastblk) {
#pragma unroll
        for (int kt = 0; kt < 4; ++kt)
#pragma unroll
          for (int r = 0; r < 4; ++r) {
            int kg = i * 64 + kt * 16 + g * 4 + r;
            p[kt][r] = (kg > qg) ? -1e30f : sc[kt][r];
          }
      } else {
#pragma unroll
        for (int kt = 0; kt < 4; ++kt)
#pragma unroll
          for (int r = 0; r < 4; ++r) p[kt][r] = sc[kt][r];
      }

      float mm = p[0][0];
#pragma unroll
      for (int kt = 0; kt < 4; ++kt)
#pragma unroll
        for (int r = 0; r < 4; ++r) mm = fmaxf(mm, p[kt][r]);
      mm = fmaxf(mm, __shfl_xor(mm, 16));
      mm = fmaxf(mm, __shfl_xor(mm, 32));

      float rs = 0.f;
      if (__any(mm > m + 8.f)) {
        const float mn = fmaxf(m, mm);
        const float corr = exp2f(m - mn);
        m = mn;
#pragma unroll
        for (int kt = 0; kt < 4; ++kt)
#pragma unroll
          for (int r = 0; r < 4; ++r) { p[kt][r] = exp2f(p[kt][r] - m); rs += p[kt][r]; }
        rs += __shfl_xor(rs, 16);
        rs += __shfl_xor(rs, 32);
        lsum = lsum * corr + rs;
#pragma unroll
        for (int nt = 0; nt < 8; ++nt)
#pragma unroll
          for (int r = 0; r < 4; ++r) acc_o[nt][r] *= corr;
      } else {
#pragma unroll
        for (int kt = 0; kt < 4; ++kt)
#pragma unroll
          for (int r = 0; r < 4; ++r) { p[kt][r] = exp2f(p[kt][r] - m); rs += p[kt][r]; }
        rs += __shfl_xor(rs, 16);
        rs += __shfl_xor(rs, 32);
        lsum += rs;
      }

      bf16x8 pb[2];
#pragma unroll
      for (int kc = 0; kc < 2; ++kc) {
        union { u32 d[4]; bf16x8 v; } u;
        u.d[0] = pkbf(p[2 * kc][0], p[2 * kc][1]);
        u.d[1] = pkbf(p[2 * kc][2], p[2 * kc][3]);
        u.d[2] = pkbf(p[2 * kc + 1][0], p[2 * kc + 1][1]);
        u.d[3] = pkbf(p[2 * kc + 1][2], p[2 * kc + 1][3]);
        pb[kc] = u.v;
      }

      __builtin_amdgcn_s_setprio(1);
#pragma unroll
      for (int nt = 0; nt < 8; ++nt) {
        const int vrow = nt * 16 + lrow;
        const char* vbase = (const char*)(&Vs[cur][vrow * 64]);
        const unsigned sw2 = (unsigned)((vrow & 7) << 4);
#pragma unroll
        for (int kc = 0; kc < 2; ++kc) {
          bf16x8 vf = *(const bf16x8*)(vbase + ((unsigned)((lk8 + kc * 32) << 1) ^ sw2));
          acc_o[nt] = __builtin_amdgcn_mfma_f32_16x16x32_bf16(vf, pb[kc], acc_o[nt], 0, 0, 0);
        }
      }
      __builtin_amdgcn_s_setprio(0);
      __builtin_amdgcn_s_barrier();
    }

    const float inv_l = 1.f / lsum;
#pragma unroll
    for (int nt = 0; nt < 8; ++nt) {
      us4 ov;
#pragma unroll
      for (int r = 0; r < 4; ++r) ov[r] = f2bf(acc_o[nt][r] * inv_l);
      *(us4*)(AO + ((size_t)(bb * 2048 + qg)) * 2048 + h * 128 + nt * 16 + g * 4) = ov;
    }
  }
}

// ---------------- launch ----------------
extern "C" void kernel_launch(void* const* d_in, const int* in_sizes, int n_in,
                              void* d_out, int out_size, void* d_ws, size_t ws_size,
                              hipStream_t stream) {
  const float* x    = (const float*)d_in[0];
  const float* cosT = (const float*)d_in[1];
  const float* sinT = (const float*)d_in[2];
  const float* Wq   = (const float*)d_in[4];
  const float* bq   = (const float*)d_in[5];
  const float* Wk   = (const float*)d_in[6];
  const float* bk   = (const float*)d_in[7];
  const float* Wv   = (const float*)d_in[8];
  const float* bv   = (const float*)d_in[9];
  const float* Wo   = (const float*)d_in[10];
  const float* bo   = (const float*)d_in[11];
  float* out = (float*)d_out;

  char* ws = (char*)d_ws;
  u16* xb  = (u16*)(ws);                    // 16 MB  [4096][2048]
  u16* Wqb = (u16*)(ws + (16u << 20));      // 8 MB
  u16* Wkb = (u16*)(ws + (24u << 20));
  u16* Wvb = (u16*)(ws + (32u << 20));
  u16* Wob = (u16*)(ws + (40u << 20));
  u16* Qb  = (u16*)(ws + (48u << 20));      // 16 MB [BH][S][HD] (pre-scaled)
  u16* Kb  = (u16*)(ws + (64u << 20));      // 16 MB [BH][S][HD] swizzled
  u16* Vtb = (u16*)(ws + (80u << 20));      // 16 MB [BH][HD][S] permuted+swizzled
  u16* AOb = (u16*)(ws + (96u << 20));      // 16 MB [4096][2048]

  cast_bf16<<<8192, 256, 0, stream>>>(x,  xb,  4096 * 2048);
  cast_bf16<<<4096, 256, 0, stream>>>(Wq, Wqb, 2048 * 2048);
  cast_bf16<<<4096, 256, 0, stream>>>(Wk, Wkb, 2048 * 2048);
  cast_bf16<<<4096, 256, 0, stream>>>(Wv, Wvb, 2048 * 2048);
  cast_bf16<<<4096, 256, 0, stream>>>(Wo, Wob, 2048 * 2048);

  // fused QKV: N = 6144, 16 m-tiles x 24 n-tiles = 384 blocks
  gemm256<<<384, 512, 0, stream>>>(xb, Wqb, Wkb, Wvb, bq, bk, bv, cosT, sinT,
                                   (void*)Qb, (void*)Kb, (void*)Vtb, 24, 1);

  attn_fwd<<<512, 256, 0, stream>>>(Qb, Kb, Vtb, AOb);

  // output proj: N = 2048, 16 x 8 = 128 blocks
  gemm256<<<128, 512, 0, stream>>>(AOb, Wob, Wob, Wob, bo, bo, bo, nullptr, nullptr,
                                   (void*)out, nullptr, nullptr, 8, 0);
}

// Round 8
// 318.895 us; speedup vs baseline: 1.1699x; 1.1699x over previous
//
#include <hip/hip_runtime.h>
#include <math.h>

typedef __attribute__((ext_vector_type(8))) __bf16 bf16x8;
typedef __attribute__((ext_vector_type(4))) float f32x4;
typedef __attribute__((ext_vector_type(4))) unsigned short us4;
typedef unsigned short u16;
typedef unsigned int u32;

#define DEVI static __device__ __forceinline__

// round-to-nearest-even fp32 -> bf16
DEVI u16 f2bf(float f) {
  union { float f; unsigned u; } v; v.f = f;
  unsigned r = v.u + 0x7fffu + ((v.u >> 16) & 1u);
  return (u16)(r >> 16);
}

DEVI void async16(const void* g, void* l) {
  __builtin_amdgcn_global_load_lds((const __attribute__((address_space(1))) void*)g,
                                   (__attribute__((address_space(3))) void*)l, 16, 0, 0);
}

// pack two f32 -> one u32 of 2 bf16 (RNE)
DEVI u32 pkbf(float lo, float hi) {
  u32 r;
  asm("v_cvt_pk_bf16_f32 %0, %1, %2" : "=v"(r) : "v"(lo), "v"(hi));
  return r;
}

// ---------------- cast fp32 -> bf16 ----------------
__global__ __launch_bounds__(256) void cast_bf16(const float* __restrict__ in,
                                                 u16* __restrict__ out, int n) {
  int i = (blockIdx.x * 256 + threadIdx.x) * 4;
  if (i >= n) return;
  float4 v = *(const float4*)(in + i);
  us4 o = { f2bf(v.x), f2bf(v.y), f2bf(v.z), f2bf(v.w) };
  *(us4*)(out + i) = o;
}

// ------- 128x128 GEMM (m97 structure, round-3 proven) + fused epilogues -----
// C[m,n] = sum_k A[m,k]*W[n,k] (+bias). 4 waves, BK=32, 2-barrier K-loop,
// global_load_lds width-16 staging. 4 blocks/CU (88 VGPR, 16KB LDS).
// qkv=1: grid (48,32), slab = blockIdx.x>>4: 0=Q rope+scale, 1=K rope+swz,
//        2=V transpose+pi-perm+swz. qkv=0: grid (16,32), slab 3 = fp32+bias.
__global__ __launch_bounds__(256, 4)
void gemm128(const u16* __restrict__ A,
             const u16* __restrict__ W0, const u16* __restrict__ W1, const u16* __restrict__ W2,
             const float* __restrict__ biasQ, const float* __restrict__ biasK,
             const float* __restrict__ biasV,
             const float* __restrict__ cosT, const float* __restrict__ sinT,
             void* __restrict__ out0, void* __restrict__ out1, void* __restrict__ out2,
             int qkv)
{
  __shared__ __align__(16) u16 As[4096];   // [128][32]
  __shared__ __align__(16) u16 Bs[4096];   // [128][32]
  const int t = threadIdx.x, w = t >> 6, lane = t & 63;
  const int lrow = lane & 15, lk8 = (lane >> 4) * 8;
  const int slab = qkv ? (blockIdx.x >> 4) : 3;
  const u16* Bp = (slab == 1) ? W1 : (slab == 2) ? W2 : W0;
  const int brow = blockIdx.y * 128, bcol = (blockIdx.x & 15) * 128;
  const int wr = (w >> 1) * 64, wc = (w & 1) * 64;

  f32x4 acc[4][4] = {};

  for (int k0 = 0; k0 < 2048; k0 += 32) {
#pragma unroll
    for (int r = 0; r < 2; ++r) {
      int e = (r * 256 + t) * 8;          // element offset in the 128x32 tile
      async16(A + (size_t)(brow + (e >> 5)) * 2048 + k0 + (e & 31), As + r * 2048 + w * 512);
      async16(Bp + (size_t)(bcol + (e >> 5)) * 2048 + k0 + (e & 31), Bs + r * 2048 + w * 512);
    }
    __syncthreads();
    bf16x8 a[4], b[4];
#pragma unroll
    for (int m = 0; m < 4; ++m) a[m] = *(const bf16x8*)(As + (wr + m * 16 + lrow) * 32 + lk8);
#pragma unroll
    for (int n = 0; n < 4; ++n) b[n] = *(const bf16x8*)(Bs + (wc + n * 16 + lrow) * 32 + lk8);
#pragma unroll
    for (int m = 0; m < 4; ++m)
#pragma unroll
      for (int n = 0; n < 4; ++n)
        acc[m][n] = __builtin_amdgcn_mfma_f32_16x16x32_bf16(a[m], b[n], acc[m][n], 0, 0, 0);
    __syncthreads();
  }

  // epilogue: C/D layout col = lane&15, row = (lane>>4)*4 + r
#pragma unroll
  for (int mi = 0; mi < 4; ++mi) {
#pragma unroll
    for (int ni = 0; ni < 4; ++ni) {
      f32x4 v = acc[mi][ni];
      const int row0 = brow + wr + mi * 16 + (lane >> 4) * 4;
      const int cols = bcol + wc + ni * 16 + lrow;
      if (slab == 3) {
        float* O = (float*)out0;
        const float bv = biasQ[cols];
#pragma unroll
        for (int r = 0; r < 4; ++r)
          O[(size_t)(row0 + r) * 2048 + cols] = v[r] + bv;
      } else if (slab == 2) {   // V -> Vt [B,H,HD,S], pi-permuted + swizzled
        u16* O = (u16*)out2;
        const float bv = biasV[cols];
        const int h = cols >> 7, d = cols & 127;
        const int bb = row0 >> 11, s = row0 & 2047;
        us4 ov;
#pragma unroll
        for (int r = 0; r < 4; ++r) ov[r] = f2bf(v[r] + bv);
        const int l = s & 63;
        const int kt = l >> 4, g2 = (l >> 2) & 3;
        const int c = ((kt >> 1) << 5) + (g2 << 3) + ((kt & 1) << 2);
        u16* base = O + ((size_t)(bb * 16 + h) * 128 + d) * 2048 + (s & ~63);
        *(us4*)((char*)base + ((unsigned)(c << 1) ^ (unsigned)((d & 7) << 4))) = ov;
      } else {                  // Q (0) / K (1): bias + RoPE
        u16* O = (u16*)(slab ? out1 : out0);
        const float bv = slab ? biasK[cols] : biasQ[cols];
        const int h = cols >> 7, d = cols & 127;
        const float sgn = (d & 1) ? 1.f : -1.f;
        const float QSCL = 0.08838834764831845f * 1.44269504088896340f;
#pragma unroll
        for (int r = 0; r < 4; ++r) {
          const int row = row0 + r, bb = row >> 11, s = row & 2047;
          float q = v[r] + bv;
          float p = __shfl_xor(q, 1);   // partner dim d^1 lives in lane^1
          float o = q * cosT[s * 128 + d] + sgn * p * sinT[s * 128 + d];
          u16* base = O + ((size_t)(bb * 16 + h) * 2048 + s) * 128;
          if (slab == 0) {
            base[d] = f2bf(o * QSCL);
          } else {
            *(u16*)((char*)base + (((unsigned)(d << 1)) ^ (unsigned)((s & 7) << 4))) = f2bf(o);
          }
        }
      }
    }
  }
}

// ---------------- causal flash attention, 2 q-sets per wave ----------------
// Q: [BH][S][128] bf16 pre-scaled by 1/sqrt(128)*log2e, K: row-swizzled,
// Vt: [BH][128][S] pi-permuted + swizzled. AO out: [4096][2048] bf16.
// Block = 4 waves x 32 q = 128-row q-tile; pair {p, 15-p} -> 34 uniform iters.
// Each wave computes TWO 16-q sets sharing every kf/vf LDS read (halves
// LDS traffic per q-row vs round-3 structure). 256 blocks, id%8 = bh%8.
__global__ __launch_bounds__(256)
void attn_fwd(const u16* __restrict__ Q, const u16* __restrict__ K,
              const u16* __restrict__ Vt, u16* __restrict__ AO)
{
  __shared__ __align__(16) u16 Ks[2][64 * 128];
  __shared__ __align__(16) u16 Vs[2][128 * 64];
  const int t = threadIdx.x, w = t >> 6, lane = t & 63;
  const int lrow = lane & 15, g = lane >> 4, lk8 = g * 8;
  const int id = blockIdx.x;
  const int bh = id & 31;     // same-bh blocks land on one XCD (id%8 = bh%8)
  const int pr = id >> 5;     // 0..7
  const u16* Qg = Q + (size_t)bh * 2048 * 128;
  const u16* Kg = K + (size_t)bh * 2048 * 128;
  const u16* Vg = Vt + (size_t)bh * 128 * 2048;
  const int bb = bh >> 4, h = bh & 15;

  auto stage = [&](int i, int b) {
#pragma unroll
    for (int r = 0; r < 4; ++r) {
      int e = (r * 256 + t) * 8;
      async16(Kg + (size_t)i * 8192 + e, &Ks[b][r * 2048 + w * 512]);
      async16(Vg + (size_t)(e >> 6) * 2048 + i * 64 + (e & 63), &Vs[b][r * 2048 + w * 512]);
    }
  };

  for (int half = 0; half < 2; ++half) {
    const int qt = half ? (15 - pr) : pr;       // 128-row q-tile index
    const int qw = qt * 128 + w * 32;           // wave's first q-row
    const int nkv = 2 * (qt + 1);
    const int qg0 = qw + lrow;                  // set-0 q-row; set-1 = +16

    bf16x8 qf[2][4];
#pragma unroll
    for (int s2 = 0; s2 < 2; ++s2)
#pragma unroll
      for (int c = 0; c < 4; ++c)
        qf[s2][c] = *(const bf16x8*)(Qg + (size_t)(qw + s2 * 16 + lrow) * 128 + lk8 + c * 32);

    f32x4 acc[2][8] = {};
    float m[2] = { -1e30f, -1e30f }, lsum[2] = { 0.f, 0.f };

    stage(0, 0);
    for (int i = 0; i < nkv; ++i) {
      const int cur = i & 1;
      const bool pfch = (i + 1) < nkv;
      if (pfch) stage(i + 1, cur ^ 1);
      if (pfch) asm volatile("s_waitcnt vmcnt(8)" ::: "memory");
      else      asm volatile("s_waitcnt vmcnt(0)" ::: "memory");
      __builtin_amdgcn_s_barrier();
      __builtin_amdgcn_sched_barrier(0);

      // QK^T swapped: C col = q (lane&15), row = k; kf shared by both q-sets
      f32x4 sc[2][4];
      __builtin_amdgcn_s_setprio(1);
#pragma unroll
      for (int kt = 0; kt < 4; ++kt) {
        f32x4 s0 = {}, s1 = {};
        const int krow = kt * 16 + lrow;
        const char* kbase = (const char*)(&Ks[cur][krow * 128]);
        const unsigned sw = (unsigned)((krow & 7) << 4);
#pragma unroll
        for (int c = 0; c < 4; ++c) {
          bf16x8 kf = *(const bf16x8*)(kbase + ((unsigned)((lk8 + c * 32) << 1) ^ sw));
          s0 = __builtin_amdgcn_mfma_f32_16x16x32_bf16(kf, qf[0][c], s0, 0, 0, 0);
          s1 = __builtin_amdgcn_mfma_f32_16x16x32_bf16(kf, qf[1][c], s1, 0, 0, 0);
        }
        sc[0][kt] = s0; sc[1][kt] = s1;
      }
      __builtin_amdgcn_s_setprio(0);

      // softmax per q-set (lane-local; defer-max THR=8)
      const bool guard = (i * 64 + 63) > qw;    // no lane can need masking otherwise
      bf16x8 pb[2][2];
#pragma unroll
      for (int s2 = 0; s2 < 2; ++s2) {
        const int qgs = qg0 + s2 * 16;
        float p[4][4];
        if (guard) {
#pragma unroll
          for (int kt = 0; kt < 4; ++kt)
#pragma unroll
            for (int r = 0; r < 4; ++r) {
              int kg = i * 64 + kt * 16 + g * 4 + r;
              p[kt][r] = (kg > qgs) ? -1e30f : sc[s2][kt][r];
            }
        } else {
#pragma unroll
          for (int kt = 0; kt < 4; ++kt)
#pragma unroll
            for (int r = 0; r < 4; ++r) p[kt][r] = sc[s2][kt][r];
        }

        float mm = p[0][0];
#pragma unroll
        for (int kt = 0; kt < 4; ++kt)
#pragma unroll
          for (int r = 0; r < 4; ++r) mm = fmaxf(mm, p[kt][r]);
        mm = fmaxf(mm, __shfl_xor(mm, 16));
        mm = fmaxf(mm, __shfl_xor(mm, 32));

        float rs = 0.f;
        if (__any(mm > m[s2] + 8.f)) {
          const float mn = fmaxf(m[s2], mm);
          const float corr = exp2f(m[s2] - mn);
          m[s2] = mn;
#pragma unroll
          for (int kt = 0; kt < 4; ++kt)
#pragma unroll
            for (int r = 0; r < 4; ++r) { p[kt][r] = exp2f(p[kt][r] - m[s2]); rs += p[kt][r]; }
          rs += __shfl_xor(rs, 16);
          rs += __shfl_xor(rs, 32);
          lsum[s2] = lsum[s2] * corr + rs;
#pragma unroll
          for (int nt = 0; nt < 8; ++nt)
#pragma unroll
            for (int r = 0; r < 4; ++r) acc[s2][nt][r] *= corr;
        } else {
#pragma unroll
          for (int kt = 0; kt < 4; ++kt)
#pragma unroll
            for (int r = 0; r < 4; ++r) { p[kt][r] = exp2f(p[kt][r] - m[s2]); rs += p[kt][r]; }
          rs += __shfl_xor(rs, 16);
          rs += __shfl_xor(rs, 32);
          lsum[s2] += rs;
        }

#pragma unroll
        for (int kc = 0; kc < 2; ++kc) {
          union { u32 d[4]; bf16x8 v; } u;
          u.d[0] = pkbf(p[2 * kc][0], p[2 * kc][1]);
          u.d[1] = pkbf(p[2 * kc][2], p[2 * kc][3]);
          u.d[2] = pkbf(p[2 * kc + 1][0], p[2 * kc + 1][1]);
          u.d[3] = pkbf(p[2 * kc + 1][2], p[2 * kc + 1][3]);
          pb[s2][kc] = u.v;
        }
      }

      // PV swapped: vf shared by both q-sets
      __builtin_amdgcn_s_setprio(1);
#pragma unroll
      for (int nt = 0; nt < 8; ++nt) {
        const int vrow = nt * 16 + lrow;
        const char* vbase = (const char*)(&Vs[cur][vrow * 64]);
        const unsigned sw2 = (unsigned)((vrow & 7) << 4);
#pragma unroll
        for (int kc = 0; kc < 2; ++kc) {
          bf16x8 vf = *(const bf16x8*)(vbase + ((unsigned)((lk8 + kc * 32) << 1) ^ sw2));
          acc[0][nt] = __builtin_amdgcn_mfma_f32_16x16x32_bf16(vf, pb[0][kc], acc[0][nt], 0, 0, 0);
          acc[1][nt] = __builtin_amdgcn_mfma_f32_16x16x32_bf16(vf, pb[1][kc], acc[1][nt], 0, 0, 0);
        }
      }
      __builtin_amdgcn_s_setprio(0);
      __builtin_amdgcn_s_barrier();
    }

    // epilogue: O[q][d = nt*16 + 4g + r] / lsum
#pragma unroll
    for (int s2 = 0; s2 < 2; ++s2) {
      const float inv_l = 1.f / lsum[s2];
      const int qgs = qg0 + s2 * 16;
#pragma unroll
      for (int nt = 0; nt < 8; ++nt) {
        us4 ov;
#pragma unroll
        for (int r = 0; r < 4; ++r) ov[r] = f2bf(acc[s2][nt][r] * inv_l);
        *(us4*)(AO + ((size_t)(bb * 2048 + qgs)) * 2048 + h * 128 + nt * 16 + g * 4) = ov;
      }
    }
  }
}

// ---------------- launch ----------------
extern "C" void kernel_launch(void* const* d_in, const int* in_sizes, int n_in,
                              void* d_out, int out_size, void* d_ws, size_t ws_size,
                              hipStream_t stream) {
  const float* x    = (const float*)d_in[0];
  const float* cosT = (const float*)d_in[1];
  const float* sinT = (const float*)d_in[2];
  const float* Wq   = (const float*)d_in[4];
  const float* bq   = (const float*)d_in[5];
  const float* Wk   = (const float*)d_in[6];
  const float* bk   = (const float*)d_in[7];
  const float* Wv   = (const float*)d_in[8];
  const float* bv   = (const float*)d_in[9];
  const float* Wo   = (const float*)d_in[10];
  const float* bo   = (const float*)d_in[11];
  float* out = (float*)d_out;

  char* ws = (char*)d_ws;
  u16* xb  = (u16*)(ws);                    // 16 MB  [4096][2048]
  u16* Wqb = (u16*)(ws + (16u << 20));      // 8 MB
  u16* Wkb = (u16*)(ws + (24u << 20));
  u16* Wvb = (u16*)(ws + (32u << 20));
  u16* Wob = (u16*)(ws + (40u << 20));
  u16* Qb  = (u16*)(ws + (48u << 20));      // 16 MB [BH][S][HD] (pre-scaled)
  u16* Kb  = (u16*)(ws + (64u << 20));      // 16 MB [BH][S][HD] swizzled
  u16* Vtb = (u16*)(ws + (80u << 20));      // 16 MB [BH][HD][S] permuted+swizzled
  u16* AOb = (u16*)(ws + (96u << 20));      // 16 MB [4096][2048]

  cast_bf16<<<8192, 256, 0, stream>>>(x,  xb,  4096 * 2048);
  cast_bf16<<<4096, 256, 0, stream>>>(Wq, Wqb, 2048 * 2048);
  cast_bf16<<<4096, 256, 0, stream>>>(Wk, Wkb, 2048 * 2048);
  cast_bf16<<<4096, 256, 0, stream>>>(Wv, Wvb, 2048 * 2048);
  cast_bf16<<<4096, 256, 0, stream>>>(Wo, Wob, 2048 * 2048);

  // fused QKV: grid (48, 32): x = slab*16 + n-tile, y = m-tile
  gemm128<<<dim3(48, 32), 256, 0, stream>>>(xb, Wqb, Wkb, Wvb, bq, bk, bv,
                                            cosT, sinT,
                                            (void*)Qb, (void*)Kb, (void*)Vtb, 1);

  attn_fwd<<<256, 256, 0, stream>>>(Qb, Kb, Vtb, AOb);

  // output proj: grid (16, 32), fp32 out + bias
  gemm128<<<dim3(16, 32), 256, 0, stream>>>(AOb, Wob, Wob, Wob, bo, bo, bo,
                                            nullptr, nullptr,
                                            (void*)out, nullptr, nullptr, 0);
}

// Round 9
// 318.796 us; speedup vs baseline: 1.1702x; 1.0003x over previous
//
#include <hip/hip_runtime.h>
#include <math.h>

typedef __attribute__((ext_vector_type(8))) __bf16 bf16x8;
typedef __attribute__((ext_vector_type(4))) float f32x4;
typedef __attribute__((ext_vector_type(4))) unsigned short us4;
typedef unsigned short u16;
typedef unsigned int u32;

#define DEVI static __device__ __forceinline__

// round-to-nearest-even fp32 -> bf16
DEVI u16 f2bf(float f) {
  union { float f; unsigned u; } v; v.f = f;
  unsigned r = v.u + 0x7fffu + ((v.u >> 16) & 1u);
  return (u16)(r >> 16);
}

DEVI void async16(const void* g, void* l) {
  __builtin_amdgcn_global_load_lds((const __attribute__((address_space(1))) void*)g,
                                   (__attribute__((address_space(3))) void*)l, 16, 0, 0);
}

// pack two f32 -> one u32 of 2 bf16 (RNE)
DEVI u32 pkbf(float lo, float hi) {
  u32 r;
  asm("v_cvt_pk_bf16_f32 %0, %1, %2" : "=v"(r) : "v"(lo), "v"(hi));
  return r;
}

// ---------------- cast fp32 -> bf16 ----------------
__global__ __launch_bounds__(256) void cast_bf16(const float* __restrict__ in,
                                                 u16* __restrict__ out, int n) {
  int i = (blockIdx.x * 256 + threadIdx.x) * 4;
  if (i >= n) return;
  float4 v = *(const float4*)(in + i);
  us4 o = { f2bf(v.x), f2bf(v.y), f2bf(v.z), f2bf(v.w) };
  *(us4*)(out + i) = o;
}

// ---------------- GEMM: C[m,n] = sum_k A[m,k]*B[n,k] (+bias) ----------------
// Round-3 proven structure: 128x128 tile, BK=32, 4 waves, 2-barrier K-loop,
// global_load_lds width-16, (256,2). ~46us per 2048x4096x2048 launch.
// MODE 0: Q  -> rope * (1/sqrt(128)*log2e), store bf16 [B,H,S,HD]
// MODE 1: K  -> rope, store bf16 [B,H,S,HD] with per-row XOR swizzle
// MODE 2: V  -> store bf16 transposed [B,H,HD,S], pi-permuted cols + swizzle
// MODE 3: O  -> store fp32 [4096][2048] + bias
template<int MODE>
__global__ __launch_bounds__(256, 2)
void gemm_bt(const u16* __restrict__ A, const u16* __restrict__ B,
             const float* __restrict__ bias,
             const float* __restrict__ cosT, const float* __restrict__ sinT,
             void* __restrict__ outp)
{
  __shared__ __align__(16) u16 As[4096];   // [128][32]
  __shared__ __align__(16) u16 Bs[4096];   // [128][32]
  const int t = threadIdx.x, w = t >> 6, lane = t & 63;
  const int lrow = lane & 15, lk8 = (lane >> 4) * 8;
  const int brow = blockIdx.y * 128, bcol = blockIdx.x * 128;
  const int wr = (w >> 1) * 64, wc = (w & 1) * 64;

  f32x4 acc[4][4] = {};

  for (int k0 = 0; k0 < 2048; k0 += 32) {
#pragma unroll
    for (int r = 0; r < 2; ++r) {
      int e = (r * 256 + t) * 8;          // element offset in the 128x32 tile
      async16(A + (size_t)(brow + (e >> 5)) * 2048 + k0 + (e & 31), As + r * 2048 + w * 512);
      async16(B + (size_t)(bcol + (e >> 5)) * 2048 + k0 + (e & 31), Bs + r * 2048 + w * 512);
    }
    __syncthreads();
    bf16x8 a[4], b[4];
#pragma unroll
    for (int m = 0; m < 4; ++m) a[m] = *(const bf16x8*)(As + (wr + m * 16 + lrow) * 32 + lk8);
#pragma unroll
    for (int n = 0; n < 4; ++n) b[n] = *(const bf16x8*)(Bs + (wc + n * 16 + lrow) * 32 + lk8);
#pragma unroll
    for (int m = 0; m < 4; ++m)
#pragma unroll
      for (int n = 0; n < 4; ++n)
        acc[m][n] = __builtin_amdgcn_mfma_f32_16x16x32_bf16(a[m], b[n], acc[m][n], 0, 0, 0);
    __syncthreads();
  }

  // epilogue: C/D layout col = lane&15, row = (lane>>4)*4 + r
#pragma unroll
  for (int mi = 0; mi < 4; ++mi) {
#pragma unroll
    for (int ni = 0; ni < 4; ++ni) {
      f32x4 v = acc[mi][ni];
      const int row0 = brow + wr + mi * 16 + (lane >> 4) * 4;
      const int col = bcol + wc + ni * 16 + lrow;
      if constexpr (MODE == 3) {
        float* O = (float*)outp;
        const float bv = bias[col];
#pragma unroll
        for (int r = 0; r < 4; ++r)
          O[(size_t)(row0 + r) * 2048 + col] = v[r] + bv;
      } else if constexpr (MODE == 0 || MODE == 1) {
        u16* O = (u16*)outp;
        const float bv = bias[col];
        const int h = col >> 7, d = col & 127;
        const float sgn = (d & 1) ? 1.f : -1.f;
        const float QSCL = 0.08838834764831845f * 1.44269504088896340f;
#pragma unroll
        for (int r = 0; r < 4; ++r) {
          const int row = row0 + r, bb = row >> 11, s = row & 2047;
          float q = v[r] + bv;
          float p = __shfl_xor(q, 1);   // partner dim d^1 lives in lane^1
          float o = q * cosT[s * 128 + d] + sgn * p * sinT[s * 128 + d];
          if constexpr (MODE == 0) o *= QSCL;
          u16* base = O + ((size_t)(bb * 16 + h) * 2048 + s) * 128;
          if constexpr (MODE == 0) {
            base[d] = f2bf(o);
          } else {
            *(u16*)((char*)base + (((unsigned)(d << 1)) ^ (unsigned)((s & 7) << 4))) = f2bf(o);
          }
        }
      } else { // MODE 2: V -> Vt [B,H,HD,S], pi-permuted within each 64-col block
        u16* O = (u16*)outp;
        const float bv = bias[col];
        const int h = col >> 7, d = col & 127;
        const int bb = row0 >> 11, s = row0 & 2047;
        us4 ov;
#pragma unroll
        for (int r = 0; r < 4; ++r) ov[r] = f2bf(v[r] + bv);
        // logical offset l = s&63 -> physical slot c = 32*(kt>>1) + 8*g + 4*(kt&1)
        const int l = s & 63;
        const int kt = l >> 4, g2 = (l >> 2) & 3;
        const int c = ((kt >> 1) << 5) + (g2 << 3) + ((kt & 1) << 2);
        u16* base = O + ((size_t)(bb * 16 + h) * 128 + d) * 2048 + (s & ~63);
        *(us4*)((char*)base + ((unsigned)(c << 1) ^ (unsigned)((d & 7) << 4))) = ov;
      }
    }
  }
}

// ---------------- causal flash attention, 2 q-sets per wave ----------------
// Q: [BH][S][128] bf16 pre-scaled by 1/sqrt(128)*log2e, K: row-swizzled,
// Vt: [BH][128][S] pi-permuted + swizzled. AO out: [4096][2048] bf16.
// Block = 4 waves x 32 q = 128-row q-tile; pair {p, 15-p} -> 34 uniform iters.
// Each wave computes TWO 16-q sets sharing every kf/vf LDS read (halves
// LDS traffic per q-row). 256 blocks, id%8 = bh%8 (XCD locality).
__global__ __launch_bounds__(256)
void attn_fwd(const u16* __restrict__ Q, const u16* __restrict__ K,
              const u16* __restrict__ Vt, u16* __restrict__ AO)
{
  __shared__ __align__(16) u16 Ks[2][64 * 128];
  __shared__ __align__(16) u16 Vs[2][128 * 64];
  const int t = threadIdx.x, w = t >> 6, lane = t & 63;
  const int lrow = lane & 15, g = lane >> 4, lk8 = g * 8;
  const int id = blockIdx.x;
  const int bh = id & 31;     // same-bh blocks land on one XCD (id%8 = bh%8)
  const int pr = id >> 5;     // 0..7
  const u16* Qg = Q + (size_t)bh * 2048 * 128;
  const u16* Kg = K + (size_t)bh * 2048 * 128;
  const u16* Vg = Vt + (size_t)bh * 128 * 2048;
  const int bb = bh >> 4, h = bh & 15;

  auto stage = [&](int i, int b) {
#pragma unroll
    for (int r = 0; r < 4; ++r) {
      int e = (r * 256 + t) * 8;
      async16(Kg + (size_t)i * 8192 + e, &Ks[b][r * 2048 + w * 512]);
      async16(Vg + (size_t)(e >> 6) * 2048 + i * 64 + (e & 63), &Vs[b][r * 2048 + w * 512]);
    }
  };

  for (int half = 0; half < 2; ++half) {
    const int qt = half ? (15 - pr) : pr;       // 128-row q-tile index
    const int qw = qt * 128 + w * 32;           // wave's first q-row
    const int nkv = 2 * (qt + 1);
    const int qg0 = qw + lrow;                  // set-0 q-row; set-1 = +16

    bf16x8 qf[2][4];
#pragma unroll
    for (int s2 = 0; s2 < 2; ++s2)
#pragma unroll
      for (int c = 0; c < 4; ++c)
        qf[s2][c] = *(const bf16x8*)(Qg + (size_t)(qw + s2 * 16 + lrow) * 128 + lk8 + c * 32);

    f32x4 acc[2][8] = {};
    float m[2] = { -1e30f, -1e30f }, lsum[2] = { 0.f, 0.f };

    stage(0, 0);
    for (int i = 0; i < nkv; ++i) {
      const int cur = i & 1;
      const bool pfch = (i + 1) < nkv;
      if (pfch) stage(i + 1, cur ^ 1);
      if (pfch) asm volatile("s_waitcnt vmcnt(8)" ::: "memory");
      else      asm volatile("s_waitcnt vmcnt(0)" ::: "memory");
      __builtin_amdgcn_s_barrier();
      __builtin_amdgcn_sched_barrier(0);

      // QK^T swapped: C col = q (lane&15), row = k; kf shared by both q-sets
      f32x4 sc[2][4];
      __builtin_amdgcn_s_setprio(1);
#pragma unroll
      for (int kt = 0; kt < 4; ++kt) {
        f32x4 s0 = {}, s1 = {};
        const int krow = kt * 16 + lrow;
        const char* kbase = (const char*)(&Ks[cur][krow * 128]);
        const unsigned sw = (unsigned)((krow & 7) << 4);
#pragma unroll
        for (int c = 0; c < 4; ++c) {
          bf16x8 kf = *(const bf16x8*)(kbase + ((unsigned)((lk8 + c * 32) << 1) ^ sw));
          s0 = __builtin_amdgcn_mfma_f32_16x16x32_bf16(kf, qf[0][c], s0, 0, 0, 0);
          s1 = __builtin_amdgcn_mfma_f32_16x16x32_bf16(kf, qf[1][c], s1, 0, 0, 0);
        }
        sc[0][kt] = s0; sc[1][kt] = s1;
      }
      __builtin_amdgcn_s_setprio(0);

      // softmax per q-set (lane-local; defer-max THR=8)
      const bool guard = (i * 64 + 63) > qw;
      bf16x8 pb[2][2];
#pragma unroll
      for (int s2 = 0; s2 < 2; ++s2) {
        const int qgs = qg0 + s2 * 16;
        float p[4][4];
        if (guard) {
#pragma unroll
          for (int kt = 0; kt < 4; ++kt)
#pragma unroll
            for (int r = 0; r < 4; ++r) {
              int kg = i * 64 + kt * 16 + g * 4 + r;
              p[kt][r] = (kg > qgs) ? -1e30f : sc[s2][kt][r];
            }
        } else {
#pragma unroll
          for (int kt = 0; kt < 4; ++kt)
#pragma unroll
            for (int r = 0; r < 4; ++r) p[kt][r] = sc[s2][kt][r];
        }

        float mm = p[0][0];
#pragma unroll
        for (int kt = 0; kt < 4; ++kt)
#pragma unroll
          for (int r = 0; r < 4; ++r) mm = fmaxf(mm, p[kt][r]);
        mm = fmaxf(mm, __shfl_xor(mm, 16));
        mm = fmaxf(mm, __shfl_xor(mm, 32));

        float rs = 0.f;
        if (__any(mm > m[s2] + 8.f)) {
          const float mn = fmaxf(m[s2], mm);
          const float corr = exp2f(m[s2] - mn);
          m[s2] = mn;
#pragma unroll
          for (int kt = 0; kt < 4; ++kt)
#pragma unroll
            for (int r = 0; r < 4; ++r) { p[kt][r] = exp2f(p[kt][r] - m[s2]); rs += p[kt][r]; }
          rs += __shfl_xor(rs, 16);
          rs += __shfl_xor(rs, 32);
          lsum[s2] = lsum[s2] * corr + rs;
#pragma unroll
          for (int nt = 0; nt < 8; ++nt)
#pragma unroll
            for (int r = 0; r < 4; ++r) acc[s2][nt][r] *= corr;
        } else {
#pragma unroll
          for (int kt = 0; kt < 4; ++kt)
#pragma unroll
            for (int r = 0; r < 4; ++r) { p[kt][r] = exp2f(p[kt][r] - m[s2]); rs += p[kt][r]; }
          rs += __shfl_xor(rs, 16);
          rs += __shfl_xor(rs, 32);
          lsum[s2] += rs;
        }

#pragma unroll
        for (int kc = 0; kc < 2; ++kc) {
          union { u32 d[4]; bf16x8 v; } u;
          u.d[0] = pkbf(p[2 * kc][0], p[2 * kc][1]);
          u.d[1] = pkbf(p[2 * kc][2], p[2 * kc][3]);
          u.d[2] = pkbf(p[2 * kc + 1][0], p[2 * kc + 1][1]);
          u.d[3] = pkbf(p[2 * kc + 1][2], p[2 * kc + 1][3]);
          pb[s2][kc] = u.v;
        }
      }

      // PV swapped: vf shared by both q-sets
      __builtin_amdgcn_s_setprio(1);
#pragma unroll
      for (int nt = 0; nt < 8; ++nt) {
        const int vrow = nt * 16 + lrow;
        const char* vbase = (const char*)(&Vs[cur][vrow * 64]);
        const unsigned sw2 = (unsigned)((vrow & 7) << 4);
#pragma unroll
        for (int kc = 0; kc < 2; ++kc) {
          bf16x8 vf = *(const bf16x8*)(vbase + ((unsigned)((lk8 + kc * 32) << 1) ^ sw2));
          acc[0][nt] = __builtin_amdgcn_mfma_f32_16x16x32_bf16(vf, pb[0][kc], acc[0][nt], 0, 0, 0);
          acc[1][nt] = __builtin_amdgcn_mfma_f32_16x16x32_bf16(vf, pb[1][kc], acc[1][nt], 0, 0, 0);
        }
      }
      __builtin_amdgcn_s_setprio(0);
      __builtin_amdgcn_s_barrier();
    }

    // epilogue: O[q][d = nt*16 + 4g + r] / lsum
#pragma unroll
    for (int s2 = 0; s2 < 2; ++s2) {
      const float inv_l = 1.f / lsum[s2];
      const int qgs = qg0 + s2 * 16;
#pragma unroll
      for (int nt = 0; nt < 8; ++nt) {
        us4 ov;
#pragma unroll
        for (int r = 0; r < 4; ++r) ov[r] = f2bf(acc[s2][nt][r] * inv_l);
        *(us4*)(AO + ((size_t)(bb * 2048 + qgs)) * 2048 + h * 128 + nt * 16 + g * 4) = ov;
      }
    }
  }
}

// ---------------- launch ----------------
extern "C" void kernel_launch(void* const* d_in, const int* in_sizes, int n_in,
                              void* d_out, int out_size, void* d_ws, size_t ws_size,
                              hipStream_t stream) {
  const float* x    = (const float*)d_in[0];
  const float* cosT = (const float*)d_in[1];
  const float* sinT = (const float*)d_in[2];
  const float* Wq   = (const float*)d_in[4];
  const float* bq   = (const float*)d_in[5];
  const float* Wk   = (const float*)d_in[6];
  const float* bk   = (const float*)d_in[7];
  const float* Wv   = (const float*)d_in[8];
  const float* bv   = (const float*)d_in[9];
  const float* Wo   = (const float*)d_in[10];
  const float* bo   = (const float*)d_in[11];
  float* out = (float*)d_out;

  char* ws = (char*)d_ws;
  u16* xb  = (u16*)(ws);                    // 16 MB  [4096][2048]
  u16* Wqb = (u16*)(ws + (16u << 20));      // 8 MB
  u16* Wkb = (u16*)(ws + (24u << 20));
  u16* Wvb = (u16*)(ws + (32u << 20));
  u16* Wob = (u16*)(ws + (40u << 20));
  u16* Qb  = (u16*)(ws + (48u << 20));      // 16 MB [BH][S][HD] (pre-scaled)
  u16* Kb  = (u16*)(ws + (64u << 20));      // 16 MB [BH][S][HD] swizzled
  u16* Vtb = (u16*)(ws + (80u << 20));      // 16 MB [BH][HD][S] permuted+swizzled
  u16* AOb = (u16*)(ws + (96u << 20));      // 16 MB [4096][2048]

  cast_bf16<<<8192, 256, 0, stream>>>(x,  xb,  4096 * 2048);
  cast_bf16<<<4096, 256, 0, stream>>>(Wq, Wqb, 2048 * 2048);
  cast_bf16<<<4096, 256, 0, stream>>>(Wk, Wkb, 2048 * 2048);
  cast_bf16<<<4096, 256, 0, stream>>>(Wv, Wvb, 2048 * 2048);
  cast_bf16<<<4096, 256, 0, stream>>>(Wo, Wob, 2048 * 2048);

  dim3 gg(16, 32);  // N/128, M/128
  gemm_bt<0><<<gg, 256, 0, stream>>>(xb, Wqb, bq, cosT, sinT, (void*)Qb);
  gemm_bt<1><<<gg, 256, 0, stream>>>(xb, Wkb, bk, cosT, sinT, (void*)Kb);
  gemm_bt<2><<<gg, 256, 0, stream>>>(xb, Wvb, bv, nullptr, nullptr, (void*)Vtb);

  attn_fwd<<<256, 256, 0, stream>>>(Qb, Kb, Vtb, AOb);

  gemm_bt<3><<<gg, 256, 0, stream>>>(AOb, Wob, bo, nullptr, nullptr, (void*)out);
}

// Round 10
// 292.042 us; speedup vs baseline: 1.2774x; 1.0916x over previous
//
#include <hip/hip_runtime.h>
#include <math.h>

typedef __attribute__((ext_vector_type(8))) __bf16 bf16x8;
typedef __attribute__((ext_vector_type(4))) float f32x4;
typedef __attribute__((ext_vector_type(4))) unsigned short us4;
typedef unsigned short u16;
typedef unsigned int u32;

#define DEVI static __device__ __forceinline__

// round-to-nearest-even fp32 -> bf16
DEVI u16 f2bf(float f) {
  union { float f; unsigned u; } v; v.f = f;
  unsigned r = v.u + 0x7fffu + ((v.u >> 16) & 1u);
  return (u16)(r >> 16);
}

DEVI void async16(const void* g, void* l) {
  __builtin_amdgcn_global_load_lds((const __attribute__((address_space(1))) void*)g,
                                   (__attribute__((address_space(3))) void*)l, 16, 0, 0);
}

// pack two f32 -> one u32 of 2 bf16 (RNE)
DEVI u32 pkbf(float lo, float hi) {
  u32 r;
  asm("v_cvt_pk_bf16_f32 %0, %1, %2" : "=v"(r) : "v"(lo), "v"(hi));
  return r;
}

// ---------------- cast fp32 -> bf16 ----------------
__global__ __launch_bounds__(256) void cast_bf16(const float* __restrict__ in,
                                                 u16* __restrict__ out, int n) {
  int i = (blockIdx.x * 256 + threadIdx.x) * 4;
  if (i >= n) return;
  float4 v = *(const float4*)(in + i);
  us4 o = { f2bf(v.x), f2bf(v.y), f2bf(v.z), f2bf(v.w) };
  *(us4*)(out + i) = o;
}

// ------- 128x128 GEMM (m97 structure) + fused epilogues, runtime slab -------
// C[m,n] = sum_k A[m,k]*W[n,k] (+bias). 4 waves, BK=32, 2-barrier K-loop,
// global_load_lds width-16 staging. (256,2) -> 88 VGPR codegen (R3-proven).
// qkv=1: grid (48,32): slab = x>>4 (0=Q rope+scale, 1=K rope+swz,
//        2=V transpose+pi-perm+swz); 1536 blocks = ~6/CU for tail overlap.
//        48 % 8 == 0 -> all m-tiles of one n-column land on one XCD (B-panel
//        L2-resident). qkv=0: grid (16,32), slab 3 = fp32 out + bias.
__global__ __launch_bounds__(256, 2)
void gemm128(const u16* __restrict__ A,
             const u16* __restrict__ W0, const u16* __restrict__ W1, const u16* __restrict__ W2,
             const float* __restrict__ biasQ, const float* __restrict__ biasK,
             const float* __restrict__ biasV,
             const float* __restrict__ cosT, const float* __restrict__ sinT,
             void* __restrict__ out0, void* __restrict__ out1, void* __restrict__ out2,
             int qkv)
{
  __shared__ __align__(16) u16 As[4096];   // [128][32]
  __shared__ __align__(16) u16 Bs[4096];   // [128][32]
  const int t = threadIdx.x, w = t >> 6, lane = t & 63;
  const int lrow = lane & 15, lk8 = (lane >> 4) * 8;
  const int slab = qkv ? (blockIdx.x >> 4) : 3;
  const u16* Bp = (slab == 1) ? W1 : (slab == 2) ? W2 : W0;
  const int brow = blockIdx.y * 128, bcol = (blockIdx.x & 15) * 128;
  const int wr = (w >> 1) * 64, wc = (w & 1) * 64;

  f32x4 acc[4][4] = {};

  for (int k0 = 0; k0 < 2048; k0 += 32) {
#pragma unroll
    for (int r = 0; r < 2; ++r) {
      int e = (r * 256 + t) * 8;          // element offset in the 128x32 tile
      async16(A + (size_t)(brow + (e >> 5)) * 2048 + k0 + (e & 31), As + r * 2048 + w * 512);
      async16(Bp + (size_t)(bcol + (e >> 5)) * 2048 + k0 + (e & 31), Bs + r * 2048 + w * 512);
    }
    __syncthreads();
    bf16x8 a[4], b[4];
#pragma unroll
    for (int m = 0; m < 4; ++m) a[m] = *(const bf16x8*)(As + (wr + m * 16 + lrow) * 32 + lk8);
#pragma unroll
    for (int n = 0; n < 4; ++n) b[n] = *(const bf16x8*)(Bs + (wc + n * 16 + lrow) * 32 + lk8);
#pragma unroll
    for (int m = 0; m < 4; ++m)
#pragma unroll
      for (int n = 0; n < 4; ++n)
        acc[m][n] = __builtin_amdgcn_mfma_f32_16x16x32_bf16(a[m], b[n], acc[m][n], 0, 0, 0);
    __syncthreads();
  }

  // epilogue: C/D layout col = lane&15, row = (lane>>4)*4 + r
#pragma unroll
  for (int mi = 0; mi < 4; ++mi) {
#pragma unroll
    for (int ni = 0; ni < 4; ++ni) {
      f32x4 v = acc[mi][ni];
      const int row0 = brow + wr + mi * 16 + (lane >> 4) * 4;
      const int cols = bcol + wc + ni * 16 + lrow;
      if (slab == 3) {
        float* O = (float*)out0;
        const float bv = biasQ[cols];
#pragma unroll
        for (int r = 0; r < 4; ++r)
          O[(size_t)(row0 + r) * 2048 + cols] = v[r] + bv;
      } else if (slab == 2) {   // V -> Vt [B,H,HD,S], pi-permuted + swizzled
        u16* O = (u16*)out2;
        const float bv = biasV[cols];
        const int h = cols >> 7, d = cols & 127;
        const int bb = row0 >> 11, s = row0 & 2047;
        us4 ov;
#pragma unroll
        for (int r = 0; r < 4; ++r) ov[r] = f2bf(v[r] + bv);
        const int l = s & 63;
        const int kt = l >> 4, g2 = (l >> 2) & 3;
        const int c = ((kt >> 1) << 5) + (g2 << 3) + ((kt & 1) << 2);
        u16* base = O + ((size_t)(bb * 16 + h) * 128 + d) * 2048 + (s & ~63);
        *(us4*)((char*)base + ((unsigned)(c << 1) ^ (unsigned)((d & 7) << 4))) = ov;
      } else {                  // Q (0) / K (1): bias + RoPE
        u16* O = (u16*)(slab ? out1 : out0);
        const float bv = slab ? biasK[cols] : biasQ[cols];
        const int h = cols >> 7, d = cols & 127;
        const float sgn = (d & 1) ? 1.f : -1.f;
        const float QSCL = 0.08838834764831845f * 1.44269504088896340f;
#pragma unroll
        for (int r = 0; r < 4; ++r) {
          const int row = row0 + r, bb = row >> 11, s = row & 2047;
          float q = v[r] + bv;
          float p = __shfl_xor(q, 1);   // partner dim d^1 lives in lane^1
          float o = q * cosT[s * 128 + d] + sgn * p * sinT[s * 128 + d];
          u16* base = O + ((size_t)(bb * 16 + h) * 2048 + s) * 128;
          if (slab == 0) {
            base[d] = f2bf(o * QSCL);
          } else {
            *(u16*)((char*)base + (((unsigned)(d << 1)) ^ (unsigned)((s & 7) << 4))) = f2bf(o);
          }
        }
      }
    }
  }
}

// ---------------- causal flash attention (R5-proven, 75us) ----------------
// Q: [BH][S][128] bf16 pre-scaled by 1/sqrt(128)*log2e, K: row-swizzled,
// Vt: [BH][128][S] pi-permuted + swizzled. AO out: [4096][2048] bf16.
// 512 blocks (2/CU), folded pairing {p, 31-p} -> uniform 33 KV-iters.
__global__ __launch_bounds__(256, 2)
void attn_fwd(const u16* __restrict__ Q, const u16* __restrict__ K,
              const u16* __restrict__ Vt, u16* __restrict__ AO)
{
  __shared__ __align__(16) u16 Ks[2][64 * 128];
  __shared__ __align__(16) u16 Vs[2][128 * 64];
  const int t = threadIdx.x, w = t >> 6, lane = t & 63;
  const int lrow = lane & 15, g = lane >> 4, lk8 = g * 8;
  const int id = blockIdx.x;
  const int bh = (id & 7) | (((id >> 3) & 3) << 3);   // XCD-local bh grouping
  const int pr = id >> 5;                              // pair index 0..15
  const u16* Qg = Q + (size_t)bh * 2048 * 128;
  const u16* Kg = K + (size_t)bh * 2048 * 128;
  const u16* Vg = Vt + (size_t)bh * 128 * 2048;
  const int bb = bh >> 4, h = bh & 15;

  for (int half = 0; half < 2; ++half) {
    const int qt = half ? (31 - pr) : pr;
    const int q0 = qt * 64, qw = q0 + w * 16;
    const int nkv = qt + 1;
    const int qg = qw + lrow;   // this lane's q-row

    bf16x8 qf[4];
#pragma unroll
    for (int c = 0; c < 4; ++c)
      qf[c] = *(const bf16x8*)(Qg + (size_t)(qw + lrow) * 128 + lk8 + c * 32);

    f32x4 acc_o[8] = {};
    float m = -1e30f, lsum = 0.f;

    auto stage = [&](int i, int b) {
#pragma unroll
      for (int r = 0; r < 4; ++r) {
        int e = (r * 256 + t) * 8;
        async16(Kg + (size_t)i * 8192 + e, &Ks[b][r * 2048 + w * 512]);
        async16(Vg + (size_t)(e >> 6) * 2048 + i * 64 + (e & 63), &Vs[b][r * 2048 + w * 512]);
      }
    };

    stage(0, 0);
    for (int i = 0; i < nkv; ++i) {
      const int cur = i & 1;
      const bool pfch = (i + 1) < nkv;
      if (pfch) stage(i + 1, cur ^ 1);
      if (pfch) asm volatile("s_waitcnt vmcnt(8)" ::: "memory");
      else      asm volatile("s_waitcnt vmcnt(0)" ::: "memory");
      __builtin_amdgcn_s_barrier();
      __builtin_amdgcn_sched_barrier(0);

      // QK^T swapped: C col = q (lane&15), row = k
      f32x4 sc[4];
      __builtin_amdgcn_s_setprio(1);
#pragma unroll
      for (int kt = 0; kt < 4; ++kt) {
        f32x4 s = {};
        const int krow = kt * 16 + lrow;
        const char* kbase = (const char*)(&Ks[cur][krow * 128]);
        const unsigned sw = (unsigned)((krow & 7) << 4);
#pragma unroll
        for (int c = 0; c < 4; ++c) {
          bf16x8 kf = *(const bf16x8*)(kbase + ((unsigned)((lk8 + c * 32) << 1) ^ sw));
          s = __builtin_amdgcn_mfma_f32_16x16x32_bf16(kf, qf[c], s, 0, 0, 0);
        }
        sc[kt] = s;
      }
      __builtin_amdgcn_s_setprio(0);

      float p[4][4];
      const bool lastblk = (i == qt);
      if (lastblk) {
#pragma unroll
        for (int kt = 0; kt < 4; ++kt)
#pragma unroll
          for (int r = 0; r < 4; ++r) {
            int kg = i * 64 + kt * 16 + g * 4 + r;
            p[kt][r] = (kg > qg) ? -1e30f : sc[kt][r];
          }
      } else {
#pragma unroll
        for (int kt = 0; kt < 4; ++kt)
#pragma unroll
          for (int r = 0; r < 4; ++r) p[kt][r] = sc[kt][r];
      }

      float mm = p[0][0];
#pragma unroll
      for (int kt = 0; kt < 4; ++kt)
#pragma unroll
        for (int r = 0; r < 4; ++r) mm = fmaxf(mm, p[kt][r]);
      mm = fmaxf(mm, __shfl_xor(mm, 16));
      mm = fmaxf(mm, __shfl_xor(mm, 32));

      float rs = 0.f;
      if (__any(mm > m + 8.f)) {
        const float mn = fmaxf(m, mm);
        const float corr = exp2f(m - mn);
        m = mn;
#pragma unroll
        for (int kt = 0; kt < 4; ++kt)
#pragma unroll
          for (int r = 0; r < 4; ++r) { p[kt][r] = exp2f(p[kt][r] - m); rs += p[kt][r]; }
        rs += __shfl_xor(rs, 16);
        rs += __shfl_xor(rs, 32);
        lsum = lsum * corr + rs;
#pragma unroll
        for (int nt = 0; nt < 8; ++nt)
#pragma unroll
          for (int r = 0; r < 4; ++r) acc_o[nt][r] *= corr;
      } else {
#pragma unroll
        for (int kt = 0; kt < 4; ++kt)
#pragma unroll
          for (int r = 0; r < 4; ++r) { p[kt][r] = exp2f(p[kt][r] - m); rs += p[kt][r]; }
        rs += __shfl_xor(rs, 16);
        rs += __shfl_xor(rs, 32);
        lsum += rs;
      }

      bf16x8 pb[2];
#pragma unroll
      for (int kc = 0; kc < 2; ++kc) {
        union { u32 d[4]; bf16x8 v; } u;
        u.d[0] = pkbf(p[2 * kc][0], p[2 * kc][1]);
        u.d[1] = pkbf(p[2 * kc][2], p[2 * kc][3]);
        u.d[2] = pkbf(p[2 * kc + 1][0], p[2 * kc + 1][1]);
        u.d[3] = pkbf(p[2 * kc + 1][2], p[2 * kc + 1][3]);
        pb[kc] = u.v;
      }

      __builtin_amdgcn_s_setprio(1);
#pragma unroll
      for (int nt = 0; nt < 8; ++nt) {
        const int vrow = nt * 16 + lrow;
        const char* vbase = (const char*)(&Vs[cur][vrow * 64]);
        const unsigned sw2 = (unsigned)((vrow & 7) << 4);
#pragma unroll
        for (int kc = 0; kc < 2; ++kc) {
          bf16x8 vf = *(const bf16x8*)(vbase + ((unsigned)((lk8 + kc * 32) << 1) ^ sw2));
          acc_o[nt] = __builtin_amdgcn_mfma_f32_16x16x32_bf16(vf, pb[kc], acc_o[nt], 0, 0, 0);
        }
      }
      __builtin_amdgcn_s_setprio(0);
      __builtin_amdgcn_s_barrier();
    }

    const float inv_l = 1.f / lsum;
#pragma unroll
    for (int nt = 0; nt < 8; ++nt) {
      us4 ov;
#pragma unroll
      for (int r = 0; r < 4; ++r) ov[r] = f2bf(acc_o[nt][r] * inv_l);
      *(us4*)(AO + ((size_t)(bb * 2048 + qg)) * 2048 + h * 128 + nt * 16 + g * 4) = ov;
    }
  }
}

// ---------------- launch ----------------
extern "C" void kernel_launch(void* const* d_in, const int* in_sizes, int n_in,
                              void* d_out, int out_size, void* d_ws, size_t ws_size,
                              hipStream_t stream) {
  const float* x    = (const float*)d_in[0];
  const float* cosT = (const float*)d_in[1];
  const float* sinT = (const float*)d_in[2];
  const float* Wq   = (const float*)d_in[4];
  const float* bq   = (const float*)d_in[5];
  const float* Wk   = (const float*)d_in[6];
  const float* bk   = (const float*)d_in[7];
  const float* Wv   = (const float*)d_in[8];
  const float* bv   = (const float*)d_in[9];
  const float* Wo   = (const float*)d_in[10];
  const float* bo   = (const float*)d_in[11];
  float* out = (float*)d_out;

  char* ws = (char*)d_ws;
  u16* xb  = (u16*)(ws);                    // 16 MB  [4096][2048]
  u16* Wqb = (u16*)(ws + (16u << 20));      // 8 MB
  u16* Wkb = (u16*)(ws + (24u << 20));
  u16* Wvb = (u16*)(ws + (32u << 20));
  u16* Wob = (u16*)(ws + (40u << 20));
  u16* Qb  = (u16*)(ws + (48u << 20));      // 16 MB [BH][S][HD] (pre-scaled)
  u16* Kb  = (u16*)(ws + (64u << 20));      // 16 MB [BH][S][HD] swizzled
  u16* Vtb = (u16*)(ws + (80u << 20));      // 16 MB [BH][HD][S] permuted+swizzled
  u16* AOb = (u16*)(ws + (96u << 20));      // 16 MB [4096][2048]

  cast_bf16<<<8192, 256, 0, stream>>>(x,  xb,  4096 * 2048);
  cast_bf16<<<4096, 256, 0, stream>>>(Wq, Wqb, 2048 * 2048);
  cast_bf16<<<4096, 256, 0, stream>>>(Wk, Wkb, 2048 * 2048);
  cast_bf16<<<4096, 256, 0, stream>>>(Wv, Wvb, 2048 * 2048);
  cast_bf16<<<4096, 256, 0, stream>>>(Wo, Wob, 2048 * 2048);

  // fused QKV: grid (48, 32): x = slab*16 + n-tile, y = m-tile (1536 blocks)
  gemm128<<<dim3(48, 32), 256, 0, stream>>>(xb, Wqb, Wkb, Wvb, bq, bk, bv,
                                            cosT, sinT,
                                            (void*)Qb, (void*)Kb, (void*)Vtb, 1);

  attn_fwd<<<512, 256, 0, stream>>>(Qb, Kb, Vtb, AOb);

  // output proj: grid (16, 32), fp32 out + bias
  gemm128<<<dim3(16, 32), 256, 0, stream>>>(AOb, Wob, Wob, Wob, bo, bo, bo,
                                            nullptr, nullptr,
                                            (void*)out, nullptr, nullptr, 0);
}

// Round 11
// 246.847 us; speedup vs baseline: 1.5113x; 1.1831x over previous
//
#include <hip/hip_runtime.h>
#include <math.h>

typedef __attribute__((ext_vector_type(8))) __bf16 bf16x8;
typedef __attribute__((ext_vector_type(4))) float f32x4;
typedef __attribute__((ext_vector_type(4))) unsigned short us4;
typedef unsigned short u16;
typedef unsigned int u32;

#define DEVI static __device__ __forceinline__

// round-to-nearest-even fp32 -> bf16
DEVI u16 f2bf(float f) {
  union { float f; unsigned u; } v; v.f = f;
  unsigned r = v.u + 0x7fffu + ((v.u >> 16) & 1u);
  return (u16)(r >> 16);
}

DEVI void async16(const void* g, void* l) {
  __builtin_amdgcn_global_load_lds((const __attribute__((address_space(1))) void*)g,
                                   (__attribute__((address_space(3))) void*)l, 16, 0, 0);
}

// pack two f32 -> one u32 of 2 bf16 (RNE)
DEVI u32 pkbf(float lo, float hi) {
  u32 r;
  asm("v_cvt_pk_bf16_f32 %0, %1, %2" : "=v"(r) : "v"(lo), "v"(hi));
  return r;
}

// ---------------- fused cast fp32 -> bf16 (x + 4 weights, one launch) -------
__global__ __launch_bounds__(256)
void cast_all(const float* __restrict__ x,
              const float* __restrict__ wq, const float* __restrict__ wk,
              const float* __restrict__ wv, const float* __restrict__ wo,
              u16* __restrict__ xb, u16* __restrict__ wqb, u16* __restrict__ wkb,
              u16* __restrict__ wvb, u16* __restrict__ wob)
{
  const int NX = 4096 * 2048, NW = 2048 * 2048;
  int i = (blockIdx.x * 256 + threadIdx.x) * 4;
  const float* src; u16* dst; int off;
  if (i < NX)               { src = x;  dst = xb;  off = i; }
  else if (i < NX + NW)     { src = wq; dst = wqb; off = i - NX; }
  else if (i < NX + 2 * NW) { src = wk; dst = wkb; off = i - NX - NW; }
  else if (i < NX + 3 * NW) { src = wv; dst = wvb; off = i - NX - 2 * NW; }
  else                      { src = wo; dst = wob; off = i - NX - 3 * NW; }
  float4 v = *(const float4*)(src + off);
  us4 o = { f2bf(v.x), f2bf(v.y), f2bf(v.z), f2bf(v.w) };
  *(us4*)(dst + off) = o;
}

// ---------------- GEMM: C[m,n] = sum_k A[m,k]*B[n,k] (+bias) ----------------
// m97 template with BK=64: 128x128 tile, 4 waves, 2-barrier K-loop (32 -> 16
// barrier drains), global_load_lds width-16. LDS [128][64] XOR-swizzled
// (row&7)<<4 via inverse-swizzled GLOBAL source + linear LDS dest (G21);
// conflict-free ds_read_b128. kk-split fragment reads cap VGPR.
// MODE 0: Q  -> rope * (1/sqrt(128)*log2e), bf16 [B,H,S,HD]
// MODE 1: K  -> rope, bf16 [B,H,S,HD] + per-row XOR swizzle
// MODE 2: V  -> bf16 transposed [B,H,HD,S], pi-permuted cols + swizzle
// MODE 3: O  -> fp32 [4096][2048] + bias
template<int MODE>
__global__ __launch_bounds__(256, 3)
void gemm_bt(const u16* __restrict__ A, const u16* __restrict__ B,
             const float* __restrict__ bias,
             const float* __restrict__ cosT, const float* __restrict__ sinT,
             void* __restrict__ outp)
{
  __shared__ __align__(16) u16 As[8192];   // [128][64] swizzled
  __shared__ __align__(16) u16 Bs[8192];
  const int t = threadIdx.x, w = t >> 6, lane = t & 63;
  const int lrow = lane & 15, lk8 = (lane >> 4) * 8;
  const int brow = blockIdx.y * 128, bcol = blockIdx.x * 128;
  const int wr = (w >> 1) * 64, wc = (w & 1) * 64;

  // staging: thread t stages 4x16B per tile per operand; LDS dest linear at
  // byte q=(r*256+t)*16; global source column inverse-swizzled.
  u32 sA[4], sB[4];
#pragma unroll
  for (int r = 0; r < 4; ++r) {
    const int q = (r * 256 + t) * 16;
    const int row = q >> 7;
    const int cb = (q ^ ((row & 7) << 4)) & 127;   // logical col byte
    sA[r] = (u32)((brow + row) * 2048 + (cb >> 1));
    sB[r] = (u32)((bcol + row) * 2048 + (cb >> 1));
  }

  // fragment read offsets (physical bytes, swizzled)
  int offA[4][2], offB[4][2];
#pragma unroll
  for (int m = 0; m < 4; ++m)
#pragma unroll
    for (int kk = 0; kk < 2; ++kk) {
      int row = wr + m * 16 + lrow;
      offA[m][kk] = (row * 128 + (kk * 32 + lk8) * 2) ^ ((row & 7) << 4);
      row = wc + m * 16 + lrow;
      offB[m][kk] = (row * 128 + (kk * 32 + lk8) * 2) ^ ((row & 7) << 4);
    }

  f32x4 acc[4][4] = {};

  for (int k0 = 0; k0 < 2048; k0 += 64) {
#pragma unroll
    for (int r = 0; r < 4; ++r) {
      async16(A + sA[r] + k0, (char*)As + (r * 256 + t) * 16);
      async16(B + sB[r] + k0, (char*)Bs + (r * 256 + t) * 16);
    }
    __syncthreads();
#pragma unroll
    for (int kk = 0; kk < 2; ++kk) {
      bf16x8 a[4], b[4];
#pragma unroll
      for (int m = 0; m < 4; ++m) a[m] = *(const bf16x8*)((char*)As + offA[m][kk]);
#pragma unroll
      for (int n = 0; n < 4; ++n) b[n] = *(const bf16x8*)((char*)Bs + offB[n][kk]);
#pragma unroll
      for (int m = 0; m < 4; ++m)
#pragma unroll
        for (int n = 0; n < 4; ++n)
          acc[m][n] = __builtin_amdgcn_mfma_f32_16x16x32_bf16(a[m], b[n], acc[m][n], 0, 0, 0);
    }
    __syncthreads();
  }

  // epilogue: C/D layout col = lane&15, row = (lane>>4)*4 + r
#pragma unroll
  for (int mi = 0; mi < 4; ++mi) {
#pragma unroll
    for (int ni = 0; ni < 4; ++ni) {
      f32x4 v = acc[mi][ni];
      const int row0 = brow + wr + mi * 16 + (lane >> 4) * 4;
      const int col = bcol + wc + ni * 16 + lrow;
      if constexpr (MODE == 3) {
        float* O = (float*)outp;
        const float bv = bias[col];
#pragma unroll
        for (int r = 0; r < 4; ++r)
          O[(size_t)(row0 + r) * 2048 + col] = v[r] + bv;
      } else if constexpr (MODE == 0 || MODE == 1) {
        u16* O = (u16*)outp;
        const float bv = bias[col];
        const int h = col >> 7, d = col & 127;
        const float sgn = (d & 1) ? 1.f : -1.f;
        const float QSCL = 0.08838834764831845f * 1.44269504088896340f;
#pragma unroll
        for (int r = 0; r < 4; ++r) {
          const int row = row0 + r, bb = row >> 11, s = row & 2047;
          float q = v[r] + bv;
          float p = __shfl_xor(q, 1);   // partner dim d^1 lives in lane^1
          float o = q * cosT[s * 128 + d] + sgn * p * sinT[s * 128 + d];
          if constexpr (MODE == 0) o *= QSCL;
          u16* base = O + ((size_t)(bb * 16 + h) * 2048 + s) * 128;
          if constexpr (MODE == 0) {
            base[d] = f2bf(o);
          } else {
            *(u16*)((char*)base + (((unsigned)(d << 1)) ^ (unsigned)((s & 7) << 4))) = f2bf(o);
          }
        }
      } else { // MODE 2: V -> Vt [B,H,HD,S], pi-permuted within each 64-col block
        u16* O = (u16*)outp;
        const float bv = bias[col];
        const int h = col >> 7, d = col & 127;
        const int bb = row0 >> 11, s = row0 & 2047;
        us4 ov;
#pragma unroll
        for (int r = 0; r < 4; ++r) ov[r] = f2bf(v[r] + bv);
        const int l = s & 63;
        const int kt = l >> 4, g2 = (l >> 2) & 3;
        const int c = ((kt >> 1) << 5) + (g2 << 3) + ((kt & 1) << 2);
        u16* base = O + ((size_t)(bb * 16 + h) * 128 + d) * 2048 + (s & ~63);
        *(us4*)((char*)base + ((unsigned)(c << 1) ^ (unsigned)((d & 7) << 4))) = ov;
      }
    }
  }
}

// ---------------- causal flash attention (R5-proven, 75us) ----------------
// Q: [BH][S][128] bf16 pre-scaled by 1/sqrt(128)*log2e, K: row-swizzled,
// Vt: [BH][128][S] pi-permuted + swizzled. AO out: [4096][2048] bf16.
// 512 blocks (2/CU), folded pairing {p, 31-p} -> uniform 33 KV-iters.
__global__ __launch_bounds__(256, 2)
void attn_fwd(const u16* __restrict__ Q, const u16* __restrict__ K,
              const u16* __restrict__ Vt, u16* __restrict__ AO)
{
  __shared__ __align__(16) u16 Ks[2][64 * 128];
  __shared__ __align__(16) u16 Vs[2][128 * 64];
  const int t = threadIdx.x, w = t >> 6, lane = t & 63;
  const int lrow = lane & 15, g = lane >> 4, lk8 = g * 8;
  const int id = blockIdx.x;
  const int bh = (id & 7) | (((id >> 3) & 3) << 3);   // XCD-local bh grouping
  const int pr = id >> 5;                              // pair index 0..15
  const u16* Qg = Q + (size_t)bh * 2048 * 128;
  const u16* Kg = K + (size_t)bh * 2048 * 128;
  const u16* Vg = Vt + (size_t)bh * 128 * 2048;
  const int bb = bh >> 4, h = bh & 15;

  for (int half = 0; half < 2; ++half) {
    const int qt = half ? (31 - pr) : pr;
    const int q0 = qt * 64, qw = q0 + w * 16;
    const int nkv = qt + 1;
    const int qg = qw + lrow;   // this lane's q-row

    bf16x8 qf[4];
#pragma unroll
    for (int c = 0; c < 4; ++c)
      qf[c] = *(const bf16x8*)(Qg + (size_t)(qw + lrow) * 128 + lk8 + c * 32);

    f32x4 acc_o[8] = {};
    float m = -1e30f, lsum = 0.f;

    auto stage = [&](int i, int b) {
#pragma unroll
      for (int r = 0; r < 4; ++r) {
        int e = (r * 256 + t) * 8;
        async16(Kg + (size_t)i * 8192 + e, &Ks[b][r * 2048 + w * 512]);
        async16(Vg + (size_t)(e >> 6) * 2048 + i * 64 + (e & 63), &Vs[b][r * 2048 + w * 512]);
      }
    };

    stage(0, 0);
    for (int i = 0; i < nkv; ++i) {
      const int cur = i & 1;
      const bool pfch = (i + 1) < nkv;
      if (pfch) stage(i + 1, cur ^ 1);
      if (pfch) asm volatile("s_waitcnt vmcnt(8)" ::: "memory");
      else      asm volatile("s_waitcnt vmcnt(0)" ::: "memory");
      __builtin_amdgcn_s_barrier();
      __builtin_amdgcn_sched_barrier(0);

      // QK^T swapped: C col = q (lane&15), row = k
      f32x4 sc[4];
      __builtin_amdgcn_s_setprio(1);
#pragma unroll
      for (int kt = 0; kt < 4; ++kt) {
        f32x4 s = {};
        const int krow = kt * 16 + lrow;
        const char* kbase = (const char*)(&Ks[cur][krow * 128]);
        const unsigned sw = (unsigned)((krow & 7) << 4);
#pragma unroll
        for (int c = 0; c < 4; ++c) {
          bf16x8 kf = *(const bf16x8*)(kbase + ((unsigned)((lk8 + c * 32) << 1) ^ sw));
          s = __builtin_amdgcn_mfma_f32_16x16x32_bf16(kf, qf[c], s, 0, 0, 0);
        }
        sc[kt] = s;
      }
      __builtin_amdgcn_s_setprio(0);

      float p[4][4];
      const bool lastblk = (i == qt);
      if (lastblk) {
#pragma unroll
        for (int kt = 0; kt < 4; ++kt)
#pragma unroll
          for (int r = 0; r < 4; ++r) {
            int kg = i * 64 + kt * 16 + g * 4 + r;
            p[kt][r] = (kg > qg) ? -1e30f : sc[kt][r];
          }
      } else {
#pragma unroll
        for (int kt = 0; kt < 4; ++kt)
#pragma unroll
          for (int r = 0; r < 4; ++r) p[kt][r] = sc[kt][r];
      }

      float mm = p[0][0];
#pragma unroll
      for (int kt = 0; kt < 4; ++kt)
#pragma unroll
        for (int r = 0; r < 4; ++r) mm = fmaxf(mm, p[kt][r]);
      mm = fmaxf(mm, __shfl_xor(mm, 16));
      mm = fmaxf(mm, __shfl_xor(mm, 32));

      float rs = 0.f;
      if (__any(mm > m + 8.f)) {
        const float mn = fmaxf(m, mm);
        const float corr = exp2f(m - mn);
        m = mn;
#pragma unroll
        for (int kt = 0; kt < 4; ++kt)
#pragma unroll
          for (int r = 0; r < 4; ++r) { p[kt][r] = exp2f(p[kt][r] - m); rs += p[kt][r]; }
        rs += __shfl_xor(rs, 16);
        rs += __shfl_xor(rs, 32);
        lsum = lsum * corr + rs;
#pragma unroll
        for (int nt = 0; nt < 8; ++nt)
#pragma unroll
          for (int r = 0; r < 4; ++r) acc_o[nt][r] *= corr;
      } else {
#pragma unroll
        for (int kt = 0; kt < 4; ++kt)
#pragma unroll
          for (int r = 0; r < 4; ++r) { p[kt][r] = exp2f(p[kt][r] - m); rs += p[kt][r]; }
        rs += __shfl_xor(rs, 16);
        rs += __shfl_xor(rs, 32);
        lsum += rs;
      }

      bf16x8 pb[2];
#pragma unroll
      for (int kc = 0; kc < 2; ++kc) {
        union { u32 d[4]; bf16x8 v; } u;
        u.d[0] = pkbf(p[2 * kc][0], p[2 * kc][1]);
        u.d[1] = pkbf(p[2 * kc][2], p[2 * kc][3]);
        u.d[2] = pkbf(p[2 * kc + 1][0], p[2 * kc + 1][1]);
        u.d[3] = pkbf(p[2 * kc + 1][2], p[2 * kc + 1][3]);
        pb[kc] = u.v;
      }

      __builtin_amdgcn_s_setprio(1);
#pragma unroll
      for (int nt = 0; nt < 8; ++nt) {
        const int vrow = nt * 16 + lrow;
        const char* vbase = (const char*)(&Vs[cur][vrow * 64]);
        const unsigned sw2 = (unsigned)((vrow & 7) << 4);
#pragma unroll
        for (int kc = 0; kc < 2; ++kc) {
          bf16x8 vf = *(const bf16x8*)(vbase + ((unsigned)((lk8 + kc * 32) << 1) ^ sw2));
          acc_o[nt] = __builtin_amdgcn_mfma_f32_16x16x32_bf16(vf, pb[kc], acc_o[nt], 0, 0, 0);
        }
      }
      __builtin_amdgcn_s_setprio(0);
      __builtin_amdgcn_s_barrier();
    }

    const float inv_l = 1.f / lsum;
#pragma unroll
    for (int nt = 0; nt < 8; ++nt) {
      us4 ov;
#pragma unroll
      for (int r = 0; r < 4; ++r) ov[r] = f2bf(acc_o[nt][r] * inv_l);
      *(us4*)(AO + ((size_t)(bb * 2048 + qg)) * 2048 + h * 128 + nt * 16 + g * 4) = ov;
    }
  }
}

// ---------------- launch ----------------
extern "C" void kernel_launch(void* const* d_in, const int* in_sizes, int n_in,
                              void* d_out, int out_size, void* d_ws, size_t ws_size,
                              hipStream_t stream) {
  const float* x    = (const float*)d_in[0];
  const float* cosT = (const float*)d_in[1];
  const float* sinT = (const float*)d_in[2];
  const float* Wq   = (const float*)d_in[4];
  const float* bq   = (const float*)d_in[5];
  const float* Wk   = (const float*)d_in[6];
  const float* bk   = (const float*)d_in[7];
  const float* Wv   = (const float*)d_in[8];
  const float* bv   = (const float*)d_in[9];
  const float* Wo   = (const float*)d_in[10];
  const float* bo   = (const float*)d_in[11];
  float* out = (float*)d_out;

  char* ws = (char*)d_ws;
  u16* xb  = (u16*)(ws);                    // 16 MB  [4096][2048]
  u16* Wqb = (u16*)(ws + (16u << 20));      // 8 MB
  u16* Wkb = (u16*)(ws + (24u << 20));
  u16* Wvb = (u16*)(ws + (32u << 20));
  u16* Wob = (u16*)(ws + (40u << 20));
  u16* Qb  = (u16*)(ws + (48u << 20));      // 16 MB [BH][S][HD] (pre-scaled)
  u16* Kb  = (u16*)(ws + (64u << 20));      // 16 MB [BH][S][HD] swizzled
  u16* Vtb = (u16*)(ws + (80u << 20));      // 16 MB [BH][HD][S] permuted+swizzled
  u16* AOb = (u16*)(ws + (96u << 20));      // 16 MB [4096][2048]

  // one fused cast: x + 4 weights (25.17M elems / 4 per thread)
  cast_all<<<24576, 256, 0, stream>>>(x, Wq, Wk, Wv, Wo, xb, Wqb, Wkb, Wvb, Wob);

  dim3 gg(16, 32);  // N/128, M/128
  gemm_bt<0><<<gg, 256, 0, stream>>>(xb, Wqb, bq, cosT, sinT, (void*)Qb);
  gemm_bt<1><<<gg, 256, 0, stream>>>(xb, Wkb, bk, cosT, sinT, (void*)Kb);
  gemm_bt<2><<<gg, 256, 0, stream>>>(xb, Wvb, bv, nullptr, nullptr, (void*)Vtb);

  attn_fwd<<<512, 256, 0, stream>>>(Qb, Kb, Vtb, AOb);

  gemm_bt<3><<<gg, 256, 0, stream>>>(AOb, Wob, bo, nullptr, nullptr, (void*)out);
}